// Round 2
// 560.759 us; speedup vs baseline: 1.8552x; 1.8552x over previous
//
#include <hip/hip_runtime.h>
#include <hip/hip_bf16.h>

#define N 8192
#define IN_DIM 512
#define OUT_DIM 64
#define ALPHA 0.2f
#define KSPLIT 4            // waves per block, each owns N/KSPLIT columns
#define LOG2E 1.44269504f

typedef __hip_bfloat16 bf16;
typedef __attribute__((ext_vector_type(8))) short bf16x8;   // 8 bf16 = 4 VGPRs (MFMA A/B frag)
typedef __attribute__((ext_vector_type(4))) float f32x4;    // MFMA C/D frag
typedef __attribute__((ext_vector_type(4))) int   int4v;
typedef __attribute__((ext_vector_type(4))) float float4v;
typedef __attribute__((ext_vector_type(4))) unsigned short ushort4v;

__device__ __forceinline__ float u2f(unsigned short u) {
    union { unsigned int i; float f; } c; c.i = ((unsigned int)u) << 16; return c.f;
}
// round-to-nearest-even fp32 -> bf16 bits (matches __float2bfloat16 for finite values)
__device__ __forceinline__ unsigned short f2bfbits(float f) {
    union { float f; unsigned int u; } c; c.f = f;
    unsigned int r = c.u + 0x7FFFu + ((c.u >> 16) & 1u);
    return (unsigned short)(r >> 16);
}

// ---------- dtype sniffer: flag=1 if float inputs are bf16, 0 if fp32 ----------
__global__ void k_sniff(const unsigned short* __restrict__ feat_u16, int* __restrict__ flag) {
    int lane = threadIdx.x;  // 64 threads, 1 wave
    float v = u2f(feat_u16[2 * lane]);
    float av = fabsf(v);
    int ok = (v == 0.f) || (av > 1e-8f && av < 1e8f);
    unsigned long long m = __ballot(ok);
    if (lane == 0) *flag = (__popcll(m) >= 48) ? 1 : 0;
}

// ---------- Kernel A: h = feat @ W ; h1 = h@a1 ; h2 = h@a2 ----------
// h is stored transposed + split into bf16 hi/lo pairs (hT[c][k]) for MFMA B-frags.
__global__ __launch_bounds__(256) void k_h(const void* __restrict__ featv,
                                           const void* __restrict__ Wv,
                                           const void* __restrict__ av,
                                           const int* __restrict__ flag,
                                           float* __restrict__ h1,
                                           float* __restrict__ h2,
                                           unsigned short* __restrict__ hT_hi,
                                           unsigned short* __restrict__ hT_lo) {
    int wave = threadIdx.x >> 6;
    int lane = threadIdx.x & 63;        // lane = output channel c
    int row = blockIdx.x * 4 + wave;
    int isbf = *flag;
    float acc0 = 0.f, acc1 = 0.f, acc2 = 0.f, acc3 = 0.f;
    float aw1, aw2;
    if (isbf) {
        const unsigned short* frow = (const unsigned short*)featv + (size_t)row * IN_DIM;
        const unsigned short* Wp = (const unsigned short*)Wv;
#pragma unroll 4
        for (int k = 0; k < IN_DIM; k += 4) {
            ushort4v f = *(const ushort4v*)(frow + k);
            acc0 += u2f(f[0]) * u2f(Wp[(k + 0) * OUT_DIM + lane]);
            acc1 += u2f(f[1]) * u2f(Wp[(k + 1) * OUT_DIM + lane]);
            acc2 += u2f(f[2]) * u2f(Wp[(k + 2) * OUT_DIM + lane]);
            acc3 += u2f(f[3]) * u2f(Wp[(k + 3) * OUT_DIM + lane]);
        }
        aw1 = u2f(((const unsigned short*)av)[lane]);
        aw2 = u2f(((const unsigned short*)av)[OUT_DIM + lane]);
    } else {
        const float* frow = (const float*)featv + (size_t)row * IN_DIM;
        const float* Wp = (const float*)Wv;
#pragma unroll 4
        for (int k = 0; k < IN_DIM; k += 4) {
            float4v f = *(const float4v*)(frow + k);
            acc0 += f[0] * Wp[(k + 0) * OUT_DIM + lane];
            acc1 += f[1] * Wp[(k + 1) * OUT_DIM + lane];
            acc2 += f[2] * Wp[(k + 2) * OUT_DIM + lane];
            acc3 += f[3] * Wp[(k + 3) * OUT_DIM + lane];
        }
        aw1 = ((const float*)av)[lane];
        aw2 = ((const float*)av)[OUT_DIM + lane];
    }
    float acc = (acc0 + acc1) + (acc2 + acc3);

    // hi/lo bf16 split, transposed store: hT[c][row] = h[row][c]
    unsigned short hb = f2bfbits(acc);
    hT_hi[(size_t)lane * N + row] = hb;
    hT_lo[(size_t)lane * N + row] = f2bfbits(acc - u2f(hb));

    float s1 = acc * aw1, s2 = acc * aw2;
#pragma unroll
    for (int off = 32; off; off >>= 1) {
        s1 += __shfl_xor(s1, off);
        s2 += __shfl_xor(s2, off);
    }
    if (lane == 0) { h1[row] = s1; h2[row] = s2; }
}

// ---------- Kernel A2: global max of h2 (makes softmax max row-independent) ----------
__global__ void k_h2max(const float* __restrict__ h2, float* __restrict__ h2max) {
    __shared__ float red[4];
    float m = -3e38f;
    for (int i = threadIdx.x; i < N; i += 256) m = fmaxf(m, h2[i]);
#pragma unroll
    for (int off = 32; off; off >>= 1) m = fmaxf(m, __shfl_xor(m, off));
    if ((threadIdx.x & 63) == 0) red[threadIdx.x >> 6] = m;
    __syncthreads();
    if (threadIdx.x == 0) *h2max = fmaxf(fmaxf(red[0], red[1]), fmaxf(red[2], red[3]));
}

// ---------- Kernel B: masked-exp GEMM via MFMA ----------
// Block = 16 rows, 4 waves splitting the N columns (K of the GEMM) into 4 segments.
// m_i = leaky(h1[i] + max_j h2[j]) is a true per-row upper bound (leaky is monotone),
// so no online rescaling; K-partials merge by addition in LDS.
// A-frag (P tile, 16x32): lane holds row=lane&15, k=k0+8*(lane>>4)+j, j=0..7.
// B-frag (h tile, 32x16): lane holds col=lane&15, same k -> single 16B load from hT.
// C-frag: col=lane&15, row=(lane>>4)*4+reg (HW-verified layout).
// Precision: w and h each split hi/lo bf16; 3 MFMAs give ~fp32-accurate products.
__global__ __launch_bounds__(256, 2) void k_attn(const int* __restrict__ adj,
                                                 const float* __restrict__ h1,
                                                 const float* __restrict__ h2,
                                                 const unsigned short* __restrict__ hT_hi,
                                                 const unsigned short* __restrict__ hT_lo,
                                                 const float* __restrict__ h2max,
                                                 const int* __restrict__ flag,
                                                 void* __restrict__ outv) {
    __shared__ float accs[KSPLIT][16][64];
    __shared__ float lred[KSPLIT][16];

    const int wave = threadIdx.x >> 6;
    const int lane = threadIdx.x & 63;
    const int rsub = lane & 15;          // A row within tile == B col (channel) within tile
    const int g = lane >> 4;             // k-group
    const int row0 = blockIdx.x * 16;
    const int row = row0 + rsub;

    const float h1r = h1[row];
    float M = h1r + *h2max;
    M = fmaxf(M, ALPHA * M);             // leaky(row-max upper bound)
    const float c0 = -M * LOG2E;

    f32x4 acc0 = {0.f, 0.f, 0.f, 0.f};
    f32x4 acc1 = {0.f, 0.f, 0.f, 0.f};
    f32x4 acc2 = {0.f, 0.f, 0.f, 0.f};
    f32x4 acc3 = {0.f, 0.f, 0.f, 0.f};
    float lacc = 0.f;

    const size_t arow = (size_t)row * N;
    const unsigned short* bph = hT_hi + (size_t)rsub * N;
    const unsigned short* bpl = hT_lo + (size_t)rsub * N;

    const int kbeg = wave * (N / KSPLIT);
    const int kend = kbeg + (N / KSPLIT);
    for (int k0 = kbeg; k0 < kend; k0 += 32) {
        const int kb = k0 + g * 8;
        int4v aj0 = *(const int4v*)(adj + arow + kb);
        int4v aj1 = *(const int4v*)(adj + arow + kb + 4);
        float4v hA = *(const float4v*)(h2 + kb);
        float4v hB = *(const float4v*)(h2 + kb + 4);

        bf16x8 Ahi, Alo;
#pragma unroll
        for (int j = 0; j < 4; ++j) {
            float t = h1r + hA[j];
            float s = fmaxf(t, ALPHA * t);                  // LeakyReLU
            float e = exp2f(fmaf(s, LOG2E, c0));            // exp(s - M)
            float w = aj0[j] > 0 ? e : 0.f;
            lacc += w;
            unsigned short hb2 = f2bfbits(w);
            Ahi[j] = (short)hb2;
            Alo[j] = (short)f2bfbits(w - u2f(hb2));
        }
#pragma unroll
        for (int j = 0; j < 4; ++j) {
            float t = h1r + hB[j];
            float s = fmaxf(t, ALPHA * t);
            float e = exp2f(fmaf(s, LOG2E, c0));
            float w = aj1[j] > 0 ? e : 0.f;
            lacc += w;
            unsigned short hb2 = f2bfbits(w);
            Ahi[j + 4] = (short)hb2;
            Alo[j + 4] = (short)f2bfbits(w - u2f(hb2));
        }

        const unsigned short* bh = bph + kb;
        const unsigned short* bl = bpl + kb;
        bf16x8 B0h = *(const bf16x8*)(bh);
        bf16x8 B1h = *(const bf16x8*)(bh + 16 * (size_t)N);
        bf16x8 B2h = *(const bf16x8*)(bh + 32 * (size_t)N);
        bf16x8 B3h = *(const bf16x8*)(bh + 48 * (size_t)N);
        bf16x8 B0l = *(const bf16x8*)(bl);
        bf16x8 B1l = *(const bf16x8*)(bl + 16 * (size_t)N);
        bf16x8 B2l = *(const bf16x8*)(bl + 32 * (size_t)N);
        bf16x8 B3l = *(const bf16x8*)(bl + 48 * (size_t)N);

        acc0 = __builtin_amdgcn_mfma_f32_16x16x32_bf16(Ahi, B0h, acc0, 0, 0, 0);
        acc1 = __builtin_amdgcn_mfma_f32_16x16x32_bf16(Ahi, B1h, acc1, 0, 0, 0);
        acc2 = __builtin_amdgcn_mfma_f32_16x16x32_bf16(Ahi, B2h, acc2, 0, 0, 0);
        acc3 = __builtin_amdgcn_mfma_f32_16x16x32_bf16(Ahi, B3h, acc3, 0, 0, 0);
        acc0 = __builtin_amdgcn_mfma_f32_16x16x32_bf16(Ahi, B0l, acc0, 0, 0, 0);
        acc1 = __builtin_amdgcn_mfma_f32_16x16x32_bf16(Ahi, B1l, acc1, 0, 0, 0);
        acc2 = __builtin_amdgcn_mfma_f32_16x16x32_bf16(Ahi, B2l, acc2, 0, 0, 0);
        acc3 = __builtin_amdgcn_mfma_f32_16x16x32_bf16(Ahi, B3l, acc3, 0, 0, 0);
        acc0 = __builtin_amdgcn_mfma_f32_16x16x32_bf16(Alo, B0h, acc0, 0, 0, 0);
        acc1 = __builtin_amdgcn_mfma_f32_16x16x32_bf16(Alo, B1h, acc1, 0, 0, 0);
        acc2 = __builtin_amdgcn_mfma_f32_16x16x32_bf16(Alo, B2h, acc2, 0, 0, 0);
        acc3 = __builtin_amdgcn_mfma_f32_16x16x32_bf16(Alo, B3h, acc3, 0, 0, 0);
    }

    // denominator: sum this lane's 8 w's happened in lacc; fold k-groups
    lacc += __shfl_xor(lacc, 16);
    lacc += __shfl_xor(lacc, 32);
    if (g == 0) lred[wave][rsub] = lacc;

#pragma unroll
    for (int r = 0; r < 4; ++r) {
        accs[wave][g * 4 + r][rsub]      = acc0[r];
        accs[wave][g * 4 + r][16 + rsub] = acc1[r];
        accs[wave][g * 4 + r][32 + rsub] = acc2[r];
        accs[wave][g * 4 + r][48 + rsub] = acc3[r];
    }
    __syncthreads();

    // merge KSPLIT partials + normalize + ELU + store (k_out fused away)
    const int isbf = *flag;
#pragma unroll
    for (int p = 0; p < (16 * 64) / 256; ++p) {
        int idx = p * 256 + threadIdx.x;
        int rl = idx >> 6, col = idx & 63;
        float v = 0.f, l = 0.f;
#pragma unroll
        for (int w2 = 0; w2 < KSPLIT; ++w2) {
            v += accs[w2][rl][col];
            l += lred[w2][rl];
        }
        float o = l > 0.f ? v / l : 0.f;
        o = o > 0.f ? o : exp2f(o * LOG2E) - 1.f;           // ELU
        size_t oi = (size_t)(row0 + rl) * OUT_DIM + col;
        if (isbf) ((bf16*)outv)[oi] = __float2bfloat16(o);
        else      ((float*)outv)[oi] = o;
    }
}

extern "C" void kernel_launch(void* const* d_in, const int* in_sizes, int n_in,
                              void* d_out, int out_size, void* d_ws, size_t ws_size,
                              hipStream_t stream) {
    const void* feat = d_in[0];
    const int* adj = (const int*)d_in[1];
    const void* W = d_in[2];
    const void* a = d_in[3];

    char* ws = (char*)d_ws;
    int*   flag   = (int*)(ws);
    float* h2max  = (float*)(ws + 256);
    float* h1     = (float*)(ws + 4096);                  // 32 KB
    float* h2     = (float*)(ws + 36864);                 // 32 KB
    unsigned short* hT_hi = (unsigned short*)(ws + 69632);            // 1 MB
    unsigned short* hT_lo = (unsigned short*)(ws + 69632 + 1048576);  // 1 MB

    hipLaunchKernelGGL(k_sniff, dim3(1), dim3(64), 0, stream,
                       (const unsigned short*)feat, flag);
    hipLaunchKernelGGL(k_h, dim3(N / 4), dim3(256), 0, stream,
                       feat, W, a, flag, h1, h2, hT_hi, hT_lo);
    hipLaunchKernelGGL(k_h2max, dim3(1), dim3(256), 0, stream, h2, h2max);
    hipLaunchKernelGGL(k_attn, dim3(N / 16), dim3(256), 0, stream,
                       adj, h1, h2, hT_hi, hT_lo, h2max, flag, d_out);
}

// Round 3
// 510.667 us; speedup vs baseline: 2.0372x; 1.0981x over previous
//
#include <hip/hip_runtime.h>
#include <hip/hip_bf16.h>

#define N 8192
#define IN_DIM 512
#define OUT_DIM 64
#define ALPHA 0.2f
#define LOG2E 1.44269504f

typedef __hip_bfloat16 bf16;
typedef __attribute__((ext_vector_type(8))) short bf16x8;   // 8 bf16 = 4 VGPRs (MFMA A/B frag)
typedef __attribute__((ext_vector_type(4))) float f32x4;    // MFMA C/D frag
typedef __attribute__((ext_vector_type(4))) int   int4v;
typedef __attribute__((ext_vector_type(4))) float float4v;

__device__ __forceinline__ float u2f(unsigned short u) {
    union { unsigned int i; float f; } c; c.i = ((unsigned int)u) << 16; return c.f;
}

// Exact truncation hi/lo split of two fp32 into packed bf16 words.
// hi = f with low 16 mantissa bits zeroed (trunc); lo = trunc16(f - hi) (residual exact,
// its truncation error < 2^-16 relative). 4 VALU per element.
__device__ __forceinline__ uint2 splitpack2(float f0, float f1) {
    unsigned u0 = __float_as_uint(f0), u1 = __float_as_uint(f1);
    unsigned h0 = u0 & 0xFFFF0000u, h1 = u1 & 0xFFFF0000u;
    float l0 = f0 - __uint_as_float(h0);
    float l1 = f1 - __uint_as_float(h1);
    uint2 r;
    r.x = (h0 >> 16) | h1;                                             // [b0 | b1] hi
    r.y = (__float_as_uint(l0) >> 16) | (__float_as_uint(l1) & 0xFFFF0000u);  // lo
    return r;
}

__device__ __forceinline__ bf16x8 as_bf16x8(int a, int b, int c, int d) {
    union { int4v i; bf16x8 b; } u;
    u.i = (int4v){a, b, c, d};
    return u.b;
}

// ---------- dtype sniffer: flag=1 if float inputs are bf16, 0 if fp32 ----------
__global__ void k_sniff(const unsigned short* __restrict__ feat_u16, int* __restrict__ flag) {
    int lane = threadIdx.x;  // 64 threads, 1 wave
    float v = u2f(feat_u16[2 * lane]);
    float av = fabsf(v);
    int ok = (v == 0.f) || (av > 1e-8f && av < 1e8f);
    unsigned long long m = __ballot(ok);
    if (lane == 0) *flag = (__popcll(m) >= 48) ? 1 : 0;
}

// ---------- prep: W [512][64] -> WT hi/lo [64][512] bf16 (for MFMA B-frags) ----------
__global__ __launch_bounds__(256) void k_prep(const void* __restrict__ Wv,
                                              const int* __restrict__ flag,
                                              unsigned short* __restrict__ WT_hi,
                                              unsigned short* __restrict__ WT_lo) {
    int idx = blockIdx.x * 256 + threadIdx.x;     // 0..32767
    int k = idx >> 6, c = idx & 63;
    float w = (*flag) ? u2f(((const unsigned short*)Wv)[idx]) : ((const float*)Wv)[idx];
    unsigned u = __float_as_uint(w);
    unsigned hi = u & 0xFFFF0000u;
    float lo = w - __uint_as_float(hi);
    WT_hi[c * IN_DIM + k] = (unsigned short)(hi >> 16);
    WT_lo[c * IN_DIM + k] = (unsigned short)(__float_as_uint(lo) >> 16);
}

// ---------- Kernel A (MFMA): h = feat @ W; hT hi/lo; h1 = h@a1; h2 = h@a2 ----------
// One wave per block, 16 rows per wave, full K=512. Same verified frag layouts as k_attn:
// A row = lane&15, k = 8*(lane>>4)+j (feat row-contig 32B load, in-reg hi/lo split);
// B col = lane&15, same k (WT[c][k] 16B load); C col = lane&15, row = 4*(lane>>4)+reg.
__global__ __launch_bounds__(64) void k_h(const void* __restrict__ featv,
                                          const unsigned short* __restrict__ WT_hi,
                                          const unsigned short* __restrict__ WT_lo,
                                          const void* __restrict__ av,
                                          const int* __restrict__ flag,
                                          float* __restrict__ h1,
                                          float* __restrict__ h2,
                                          unsigned short* __restrict__ hT_hi,
                                          unsigned short* __restrict__ hT_lo) {
    const int lane = threadIdx.x & 63;
    const int rsub = lane & 15;
    const int g = lane >> 4;
    const int wrow0 = blockIdx.x * 16;
    const int isbf = *flag;

    f32x4 acc0 = {0.f,0.f,0.f,0.f}, acc1 = {0.f,0.f,0.f,0.f};
    f32x4 acc2 = {0.f,0.f,0.f,0.f}, acc3 = {0.f,0.f,0.f,0.f};

    for (int k0 = 0; k0 < IN_DIM; k0 += 32) {
        const int ka = k0 + g * 8;
        bf16x8 Ah, Al;
        if (isbf) {
            Ah = *(const bf16x8*)((const unsigned short*)featv + (size_t)(wrow0 + rsub) * IN_DIM + ka);
            Al = as_bf16x8(0, 0, 0, 0);
        } else {
            const float* fp = (const float*)featv + (size_t)(wrow0 + rsub) * IN_DIM + ka;
            float4v f0 = *(const float4v*)fp;
            float4v f1 = *(const float4v*)(fp + 4);
            uint2 q0 = splitpack2(f0[0], f0[1]);
            uint2 q1 = splitpack2(f0[2], f0[3]);
            uint2 q2 = splitpack2(f1[0], f1[1]);
            uint2 q3 = splitpack2(f1[2], f1[3]);
            Ah = as_bf16x8((int)q0.x, (int)q1.x, (int)q2.x, (int)q3.x);
            Al = as_bf16x8((int)q0.y, (int)q1.y, (int)q2.y, (int)q3.y);
        }
        const unsigned short* wh = WT_hi + (size_t)rsub * IN_DIM + ka;
        const unsigned short* wl = WT_lo + (size_t)rsub * IN_DIM + ka;
        bf16x8 B0h = *(const bf16x8*)(wh);
        bf16x8 B1h = *(const bf16x8*)(wh + 16 * IN_DIM);
        bf16x8 B2h = *(const bf16x8*)(wh + 32 * IN_DIM);
        bf16x8 B3h = *(const bf16x8*)(wh + 48 * IN_DIM);
        bf16x8 B0l = *(const bf16x8*)(wl);
        bf16x8 B1l = *(const bf16x8*)(wl + 16 * IN_DIM);
        bf16x8 B2l = *(const bf16x8*)(wl + 32 * IN_DIM);
        bf16x8 B3l = *(const bf16x8*)(wl + 48 * IN_DIM);

        acc0 = __builtin_amdgcn_mfma_f32_16x16x32_bf16(Ah, B0h, acc0, 0, 0, 0);
        acc1 = __builtin_amdgcn_mfma_f32_16x16x32_bf16(Ah, B1h, acc1, 0, 0, 0);
        acc2 = __builtin_amdgcn_mfma_f32_16x16x32_bf16(Ah, B2h, acc2, 0, 0, 0);
        acc3 = __builtin_amdgcn_mfma_f32_16x16x32_bf16(Ah, B3h, acc3, 0, 0, 0);
        acc0 = __builtin_amdgcn_mfma_f32_16x16x32_bf16(Ah, B0l, acc0, 0, 0, 0);
        acc1 = __builtin_amdgcn_mfma_f32_16x16x32_bf16(Ah, B1l, acc1, 0, 0, 0);
        acc2 = __builtin_amdgcn_mfma_f32_16x16x32_bf16(Ah, B2l, acc2, 0, 0, 0);
        acc3 = __builtin_amdgcn_mfma_f32_16x16x32_bf16(Ah, B3l, acc3, 0, 0, 0);
        acc0 = __builtin_amdgcn_mfma_f32_16x16x32_bf16(Al, B0h, acc0, 0, 0, 0);
        acc1 = __builtin_amdgcn_mfma_f32_16x16x32_bf16(Al, B1h, acc1, 0, 0, 0);
        acc2 = __builtin_amdgcn_mfma_f32_16x16x32_bf16(Al, B2h, acc2, 0, 0, 0);
        acc3 = __builtin_amdgcn_mfma_f32_16x16x32_bf16(Al, B3h, acc3, 0, 0, 0);
    }

    // ---- hT hi/lo transposed store: lane holds rows wrow0+g*4+0..3 of col ct*16+rsub ----
    {
        uint2 s01, s23;
        size_t off;
        s01 = splitpack2(acc0[0], acc0[1]); s23 = splitpack2(acc0[2], acc0[3]);
        off = (size_t)(0 * 16 + rsub) * N + wrow0 + g * 4;
        { uint2 ph; ph.x = s01.x; ph.y = s23.x; *(uint2*)(hT_hi + off) = ph; }
        { uint2 pl; pl.x = s01.y; pl.y = s23.y; *(uint2*)(hT_lo + off) = pl; }
        s01 = splitpack2(acc1[0], acc1[1]); s23 = splitpack2(acc1[2], acc1[3]);
        off = (size_t)(1 * 16 + rsub) * N + wrow0 + g * 4;
        { uint2 ph; ph.x = s01.x; ph.y = s23.x; *(uint2*)(hT_hi + off) = ph; }
        { uint2 pl; pl.x = s01.y; pl.y = s23.y; *(uint2*)(hT_lo + off) = pl; }
        s01 = splitpack2(acc2[0], acc2[1]); s23 = splitpack2(acc2[2], acc2[3]);
        off = (size_t)(2 * 16 + rsub) * N + wrow0 + g * 4;
        { uint2 ph; ph.x = s01.x; ph.y = s23.x; *(uint2*)(hT_hi + off) = ph; }
        { uint2 pl; pl.x = s01.y; pl.y = s23.y; *(uint2*)(hT_lo + off) = pl; }
        s01 = splitpack2(acc3[0], acc3[1]); s23 = splitpack2(acc3[2], acc3[3]);
        off = (size_t)(3 * 16 + rsub) * N + wrow0 + g * 4;
        { uint2 ph; ph.x = s01.x; ph.y = s23.x; *(uint2*)(hT_hi + off) = ph; }
        { uint2 pl; pl.x = s01.y; pl.y = s23.y; *(uint2*)(hT_lo + off) = pl; }
    }

    // ---- h1/h2: per-lane partial over its 4 cols, reduce across the 16-lane group ----
    const float* af = (const float*)av;
    const unsigned short* au = (const unsigned short*)av;
    float a10 = isbf ? u2f(au[rsub])      : af[rsub];
    float a11 = isbf ? u2f(au[16 + rsub]) : af[16 + rsub];
    float a12 = isbf ? u2f(au[32 + rsub]) : af[32 + rsub];
    float a13 = isbf ? u2f(au[48 + rsub]) : af[48 + rsub];
    float a20 = isbf ? u2f(au[64 + rsub])  : af[64 + rsub];
    float a21 = isbf ? u2f(au[80 + rsub])  : af[80 + rsub];
    float a22 = isbf ? u2f(au[96 + rsub])  : af[96 + rsub];
    float a23 = isbf ? u2f(au[112 + rsub]) : af[112 + rsub];
    float s1r[4], s2r[4];
#pragma unroll
    for (int r = 0; r < 4; ++r) {
        s1r[r] = acc0[r] * a10 + acc1[r] * a11 + acc2[r] * a12 + acc3[r] * a13;
        s2r[r] = acc0[r] * a20 + acc1[r] * a21 + acc2[r] * a22 + acc3[r] * a23;
    }
#pragma unroll
    for (int off = 8; off; off >>= 1) {
#pragma unroll
        for (int r = 0; r < 4; ++r) {
            s1r[r] += __shfl_xor(s1r[r], off);
            s2r[r] += __shfl_xor(s2r[r], off);
        }
    }
    if (rsub < 4) {
        float v1 = rsub == 0 ? s1r[0] : rsub == 1 ? s1r[1] : rsub == 2 ? s1r[2] : s1r[3];
        float v2 = rsub == 0 ? s2r[0] : rsub == 1 ? s2r[1] : rsub == 2 ? s2r[2] : s2r[3];
        h1[wrow0 + g * 4 + rsub] = v1;
        h2[wrow0 + g * 4 + rsub] = v2;
    }
}

// ---------- global max of h2 ----------
__global__ void k_h2max(const float* __restrict__ h2, float* __restrict__ h2max) {
    __shared__ float red[4];
    float m = -3e38f;
    for (int i = threadIdx.x; i < N; i += 256) m = fmaxf(m, h2[i]);
#pragma unroll
    for (int off = 32; off; off >>= 1) m = fmaxf(m, __shfl_xor(m, off));
    if ((threadIdx.x & 63) == 0) red[threadIdx.x >> 6] = m;
    __syncthreads();
    if (threadIdx.x == 0) *h2max = fmaxf(fmaxf(red[0], red[1]), fmaxf(red[2], red[3]));
}

// ---------- Kernel B: masked-exp GEMM via MFMA, K split over blockIdx.y ----------
// grid (N/16, nkb): each block does 16 rows x klen columns (4 waves x klen/4 each),
// writes fp32 partial acc + denominator; k_out merges. 2048 blocks -> full occupancy.
__global__ __launch_bounds__(256, 4) void k_attn(const int* __restrict__ adj,
                                                 const float* __restrict__ h1,
                                                 const float* __restrict__ h2,
                                                 const unsigned short* __restrict__ hT_hi,
                                                 const unsigned short* __restrict__ hT_lo,
                                                 const float* __restrict__ h2max,
                                                 float* __restrict__ pacc,
                                                 float* __restrict__ plner,
                                                 int klen) {
    __shared__ float accs[4][16][64];
    __shared__ float lred[4][16];

    const int wave = threadIdx.x >> 6;
    const int lane = threadIdx.x & 63;
    const int rsub = lane & 15;
    const int g = lane >> 4;
    const int row0 = blockIdx.x * 16;
    const int row = row0 + rsub;
    const int kbid = blockIdx.y;

    const float h1r = h1[row];
    float M = h1r + *h2max;
    M = fmaxf(M, ALPHA * M);             // leaky(row-max upper bound), exact softmax shift
    const float c0 = -M * LOG2E;

    f32x4 acc0 = {0.f,0.f,0.f,0.f}, acc1 = {0.f,0.f,0.f,0.f};
    f32x4 acc2 = {0.f,0.f,0.f,0.f}, acc3 = {0.f,0.f,0.f,0.f};
    float lacc = 0.f;

    const size_t arow = (size_t)row * N;
    const unsigned short* bph = hT_hi + (size_t)rsub * N;
    const unsigned short* bpl = hT_lo + (size_t)rsub * N;

    const int kbeg = kbid * klen + wave * (klen >> 2);
    const int kend = kbeg + (klen >> 2);
    for (int k0 = kbeg; k0 < kend; k0 += 32) {
        const int kb = k0 + g * 8;
        int4v aj0 = *(const int4v*)(adj + arow + kb);
        int4v aj1 = *(const int4v*)(adj + arow + kb + 4);
        float4v hA = *(const float4v*)(h2 + kb);
        float4v hB = *(const float4v*)(h2 + kb + 4);

        float w[8];
#pragma unroll
        for (int j = 0; j < 4; ++j) {
            float t = h1r + hA[j];
            float s = fmaxf(t, ALPHA * t);                  // LeakyReLU
            float e = exp2f(fmaf(s, LOG2E, c0));            // exp(s - M), s-M <= 0
            w[j] = aj0[j] > 0 ? e : 0.f;
        }
#pragma unroll
        for (int j = 0; j < 4; ++j) {
            float t = h1r + hB[j];
            float s = fmaxf(t, ALPHA * t);
            float e = exp2f(fmaf(s, LOG2E, c0));
            w[4 + j] = aj1[j] > 0 ? e : 0.f;
        }
#pragma unroll
        for (int j = 0; j < 8; ++j) lacc += w[j];

        uint2 p0 = splitpack2(w[0], w[1]);
        uint2 p1 = splitpack2(w[2], w[3]);
        uint2 p2 = splitpack2(w[4], w[5]);
        uint2 p3 = splitpack2(w[6], w[7]);
        bf16x8 Ahi = as_bf16x8((int)p0.x, (int)p1.x, (int)p2.x, (int)p3.x);
        bf16x8 Alo = as_bf16x8((int)p0.y, (int)p1.y, (int)p2.y, (int)p3.y);

        const unsigned short* bh = bph + kb;
        const unsigned short* bl = bpl + kb;
        bf16x8 B0h = *(const bf16x8*)(bh);
        bf16x8 B1h = *(const bf16x8*)(bh + 16 * (size_t)N);
        bf16x8 B2h = *(const bf16x8*)(bh + 32 * (size_t)N);
        bf16x8 B3h = *(const bf16x8*)(bh + 48 * (size_t)N);
        bf16x8 B0l = *(const bf16x8*)(bl);
        bf16x8 B1l = *(const bf16x8*)(bl + 16 * (size_t)N);
        bf16x8 B2l = *(const bf16x8*)(bl + 32 * (size_t)N);
        bf16x8 B3l = *(const bf16x8*)(bl + 48 * (size_t)N);

        acc0 = __builtin_amdgcn_mfma_f32_16x16x32_bf16(Ahi, B0h, acc0, 0, 0, 0);
        acc1 = __builtin_amdgcn_mfma_f32_16x16x32_bf16(Ahi, B1h, acc1, 0, 0, 0);
        acc2 = __builtin_amdgcn_mfma_f32_16x16x32_bf16(Ahi, B2h, acc2, 0, 0, 0);
        acc3 = __builtin_amdgcn_mfma_f32_16x16x32_bf16(Ahi, B3h, acc3, 0, 0, 0);
        acc0 = __builtin_amdgcn_mfma_f32_16x16x32_bf16(Ahi, B0l, acc0, 0, 0, 0);
        acc1 = __builtin_amdgcn_mfma_f32_16x16x32_bf16(Ahi, B1l, acc1, 0, 0, 0);
        acc2 = __builtin_amdgcn_mfma_f32_16x16x32_bf16(Ahi, B2l, acc2, 0, 0, 0);
        acc3 = __builtin_amdgcn_mfma_f32_16x16x32_bf16(Ahi, B3l, acc3, 0, 0, 0);
        acc0 = __builtin_amdgcn_mfma_f32_16x16x32_bf16(Alo, B0h, acc0, 0, 0, 0);
        acc1 = __builtin_amdgcn_mfma_f32_16x16x32_bf16(Alo, B1h, acc1, 0, 0, 0);
        acc2 = __builtin_amdgcn_mfma_f32_16x16x32_bf16(Alo, B2h, acc2, 0, 0, 0);
        acc3 = __builtin_amdgcn_mfma_f32_16x16x32_bf16(Alo, B3h, acc3, 0, 0, 0);
    }

    lacc += __shfl_xor(lacc, 16);
    lacc += __shfl_xor(lacc, 32);
    if (g == 0) lred[wave][rsub] = lacc;

#pragma unroll
    for (int r = 0; r < 4; ++r) {
        accs[wave][g * 4 + r][rsub]      = acc0[r];
        accs[wave][g * 4 + r][16 + rsub] = acc1[r];
        accs[wave][g * 4 + r][32 + rsub] = acc2[r];
        accs[wave][g * 4 + r][48 + rsub] = acc3[r];
    }
    __syncthreads();

    float* pa = pacc + (size_t)kbid * (N * OUT_DIM);
#pragma unroll
    for (int p = 0; p < 4; ++p) {
        int idx = p * 256 + threadIdx.x;
        int rl = idx >> 6, col = idx & 63;
        float v = accs[0][rl][col] + accs[1][rl][col] + accs[2][rl][col] + accs[3][rl][col];
        pa[(size_t)(row0 + rl) * OUT_DIM + col] = v;
        if (col == 0)
            plner[(size_t)kbid * N + row0 + rl] = lred[0][rl] + lred[1][rl] + lred[2][rl] + lred[3][rl];
    }
}

// ---------- Kernel C: merge K-partials, normalize, ELU, store ----------
__global__ __launch_bounds__(256) void k_out(const float* __restrict__ pacc,
                                             const float* __restrict__ plner,
                                             const int* __restrict__ flag,
                                             void* __restrict__ outv,
                                             int nkb) {
    int idx = blockIdx.x * 256 + threadIdx.x;
    int row = idx >> 6;
    float v = 0.f, l = 0.f;
    for (int kb = 0; kb < nkb; ++kb) {
        v += pacc[(size_t)kb * (N * OUT_DIM) + idx];
        l += plner[(size_t)kb * N + row];
    }
    float o = l > 0.f ? v / l : 0.f;
    o = o > 0.f ? o : exp2f(o * LOG2E) - 1.f;               // ELU
    if (*flag) ((bf16*)outv)[idx] = __float2bfloat16(o);
    else       ((float*)outv)[idx] = o;
}

extern "C" void kernel_launch(void* const* d_in, const int* in_sizes, int n_in,
                              void* d_out, int out_size, void* d_ws, size_t ws_size,
                              hipStream_t stream) {
    const void* feat = d_in[0];
    const int* adj = (const int*)d_in[1];
    const void* W = d_in[2];
    const void* a = d_in[3];

    char* ws = (char*)d_ws;
    int*   flag   = (int*)(ws);
    float* h2max  = (float*)(ws + 256);
    float* h1     = (float*)(ws + 4096);                              // 32 KB
    float* h2     = (float*)(ws + 36864);                             // 32 KB
    unsigned short* hT_hi = (unsigned short*)(ws + 69632);            // 1 MB
    unsigned short* hT_lo = (unsigned short*)(ws + 69632 + 1048576);  // 1 MB
    unsigned short* WT_hi = (unsigned short*)(ws + 2166784);          // 64 KB
    unsigned short* WT_lo = (unsigned short*)(ws + 2166784 + 65536);  // 64 KB
    char* dynbase = ws + 2297856;

    size_t cap = ws_size ? ws_size : ((size_t)1 << 30);
    int nkb = 4;
    while (nkb > 1) {
        size_t need = 2297856 + (size_t)nkb * ((size_t)N * OUT_DIM * 4 + (size_t)N * 4);
        if (need <= cap) break;
        nkb >>= 1;
    }
    float* pacc  = (float*)dynbase;
    float* plner = (float*)(dynbase + (size_t)nkb * N * OUT_DIM * 4);

    hipLaunchKernelGGL(k_sniff, dim3(1), dim3(64), 0, stream,
                       (const unsigned short*)feat, flag);
    hipLaunchKernelGGL(k_prep, dim3((IN_DIM * OUT_DIM) / 256), dim3(256), 0, stream,
                       W, flag, WT_hi, WT_lo);
    hipLaunchKernelGGL(k_h, dim3(N / 16), dim3(64), 0, stream,
                       feat, WT_hi, WT_lo, a, flag, h1, h2, hT_hi, hT_lo);
    hipLaunchKernelGGL(k_h2max, dim3(1), dim3(256), 0, stream, h2, h2max);
    hipLaunchKernelGGL(k_attn, dim3(N / 16, nkb), dim3(256), 0, stream,
                       adj, h1, h2, hT_hi, hT_lo, h2max, pacc, plner, N / nkb);
    hipLaunchKernelGGL(k_out, dim3((N * OUT_DIM) / 256), dim3(256), 0, stream,
                       pacc, plner, flag, d_out, nkb);
}

// Round 4
// 420.148 us; speedup vs baseline: 2.4761x; 1.2154x over previous
//
#include <hip/hip_runtime.h>
#include <hip/hip_bf16.h>

#define N 8192
#define IN_DIM 512
#define OUT_DIM 64
#define ALPHA 0.2f
#define LOG2E 1.44269504f

typedef __hip_bfloat16 bf16;
typedef __attribute__((ext_vector_type(8))) short bf16x8;   // 8 bf16 = 4 VGPRs (MFMA A/B frag)
typedef __attribute__((ext_vector_type(4))) float f32x4;    // MFMA C/D frag
typedef __attribute__((ext_vector_type(4))) int   int4v;
typedef __attribute__((ext_vector_type(4))) float float4v;

__device__ __forceinline__ float u2f(unsigned short u) {
    union { unsigned int i; float f; } c; c.i = ((unsigned int)u) << 16; return c.f;
}

// Exact truncation hi/lo split of two fp32 into packed bf16 words.
__device__ __forceinline__ uint2 splitpack2(float f0, float f1) {
    unsigned u0 = __float_as_uint(f0), u1 = __float_as_uint(f1);
    unsigned h0 = u0 & 0xFFFF0000u, h1 = u1 & 0xFFFF0000u;
    float l0 = f0 - __uint_as_float(h0);
    float l1 = f1 - __uint_as_float(h1);
    uint2 r;
    r.x = (h0 >> 16) | h1;
    r.y = (__float_as_uint(l0) >> 16) | (__float_as_uint(l1) & 0xFFFF0000u);
    return r;
}

__device__ __forceinline__ bf16x8 as_bf16x8(int a, int b, int c, int d) {
    union { int4v i; bf16x8 b; } u;
    u.i = (int4v){a, b, c, d};
    return u.b;
}

// ordered-float <-> unsigned monotone encoding (for atomicMax on float)
__device__ __forceinline__ unsigned fenc(float f) {
    unsigned u = __float_as_uint(f);
    return (u & 0x80000000u) ? ~u : (u | 0x80000000u);
}
__device__ __forceinline__ float fdec(unsigned e) {
    return (e & 0x80000000u) ? __uint_as_float(e & 0x7FFFFFFFu) : __uint_as_float(~e);
}

// ---------- dtype sniffer: flag=1 if float inputs are bf16, 0 if fp32 ----------
__global__ void k_sniff(const unsigned short* __restrict__ feat_u16, int* __restrict__ flag) {
    int lane = threadIdx.x;  // 64 threads, 1 wave
    float v = u2f(feat_u16[2 * lane]);
    float av = fabsf(v);
    int ok = (v == 0.f) || (av > 1e-8f && av < 1e8f);
    unsigned long long m = __ballot(ok);
    if (lane == 0) *flag = (__popcll(m) >= 48) ? 1 : 0;
}

// ---------- prep: W [512][64] -> WT hi/lo [64][512] bf16; init h2max encoder ----------
__global__ __launch_bounds__(256) void k_prep(const void* __restrict__ Wv,
                                              const int* __restrict__ flag,
                                              unsigned short* __restrict__ WT_hi,
                                              unsigned short* __restrict__ WT_lo,
                                              unsigned* __restrict__ h2enc) {
    if (blockIdx.x == 0 && threadIdx.x == 0) *h2enc = fenc(-3e38f);
    int idx = blockIdx.x * 256 + threadIdx.x;     // 0..32767
    int k = idx >> 6, c = idx & 63;
    float w = (*flag) ? u2f(((const unsigned short*)Wv)[idx]) : ((const float*)Wv)[idx];
    unsigned u = __float_as_uint(w);
    unsigned hi = u & 0xFFFF0000u;
    float lo = w - __uint_as_float(hi);
    WT_hi[c * IN_DIM + k] = (unsigned short)(hi >> 16);
    WT_lo[c * IN_DIM + k] = (unsigned short)(__float_as_uint(lo) >> 16);
}

// ---------- Kernel A (MFMA): h = feat @ W; hT hi/lo; h1,h2 (pre-scaled by log2e) ----------
__global__ __launch_bounds__(64) void k_h(const void* __restrict__ featv,
                                          const unsigned short* __restrict__ WT_hi,
                                          const unsigned short* __restrict__ WT_lo,
                                          const void* __restrict__ av,
                                          const int* __restrict__ flag,
                                          float* __restrict__ h1,
                                          float* __restrict__ h2,
                                          unsigned short* __restrict__ hT_hi,
                                          unsigned short* __restrict__ hT_lo,
                                          unsigned* __restrict__ h2enc) {
    const int lane = threadIdx.x & 63;
    const int rsub = lane & 15;
    const int g = lane >> 4;
    const int wrow0 = blockIdx.x * 16;
    const int isbf = *flag;

    f32x4 acc0 = {0.f,0.f,0.f,0.f}, acc1 = {0.f,0.f,0.f,0.f};
    f32x4 acc2 = {0.f,0.f,0.f,0.f}, acc3 = {0.f,0.f,0.f,0.f};

    for (int k0 = 0; k0 < IN_DIM; k0 += 32) {
        const int ka = k0 + g * 8;
        bf16x8 Ah, Al;
        if (isbf) {
            Ah = *(const bf16x8*)((const unsigned short*)featv + (size_t)(wrow0 + rsub) * IN_DIM + ka);
            Al = as_bf16x8(0, 0, 0, 0);
        } else {
            const float* fp = (const float*)featv + (size_t)(wrow0 + rsub) * IN_DIM + ka;
            float4v f0 = *(const float4v*)fp;
            float4v f1 = *(const float4v*)(fp + 4);
            uint2 q0 = splitpack2(f0[0], f0[1]);
            uint2 q1 = splitpack2(f0[2], f0[3]);
            uint2 q2 = splitpack2(f1[0], f1[1]);
            uint2 q3 = splitpack2(f1[2], f1[3]);
            Ah = as_bf16x8((int)q0.x, (int)q1.x, (int)q2.x, (int)q3.x);
            Al = as_bf16x8((int)q0.y, (int)q1.y, (int)q2.y, (int)q3.y);
        }
        const unsigned short* wh = WT_hi + (size_t)rsub * IN_DIM + ka;
        const unsigned short* wl = WT_lo + (size_t)rsub * IN_DIM + ka;
        bf16x8 B0h = *(const bf16x8*)(wh);
        bf16x8 B1h = *(const bf16x8*)(wh + 16 * IN_DIM);
        bf16x8 B2h = *(const bf16x8*)(wh + 32 * IN_DIM);
        bf16x8 B3h = *(const bf16x8*)(wh + 48 * IN_DIM);
        bf16x8 B0l = *(const bf16x8*)(wl);
        bf16x8 B1l = *(const bf16x8*)(wl + 16 * IN_DIM);
        bf16x8 B2l = *(const bf16x8*)(wl + 32 * IN_DIM);
        bf16x8 B3l = *(const bf16x8*)(wl + 48 * IN_DIM);

        acc0 = __builtin_amdgcn_mfma_f32_16x16x32_bf16(Ah, B0h, acc0, 0, 0, 0);
        acc1 = __builtin_amdgcn_mfma_f32_16x16x32_bf16(Ah, B1h, acc1, 0, 0, 0);
        acc2 = __builtin_amdgcn_mfma_f32_16x16x32_bf16(Ah, B2h, acc2, 0, 0, 0);
        acc3 = __builtin_amdgcn_mfma_f32_16x16x32_bf16(Ah, B3h, acc3, 0, 0, 0);
        acc0 = __builtin_amdgcn_mfma_f32_16x16x32_bf16(Ah, B0l, acc0, 0, 0, 0);
        acc1 = __builtin_amdgcn_mfma_f32_16x16x32_bf16(Ah, B1l, acc1, 0, 0, 0);
        acc2 = __builtin_amdgcn_mfma_f32_16x16x32_bf16(Ah, B2l, acc2, 0, 0, 0);
        acc3 = __builtin_amdgcn_mfma_f32_16x16x32_bf16(Ah, B3l, acc3, 0, 0, 0);
        acc0 = __builtin_amdgcn_mfma_f32_16x16x32_bf16(Al, B0h, acc0, 0, 0, 0);
        acc1 = __builtin_amdgcn_mfma_f32_16x16x32_bf16(Al, B1h, acc1, 0, 0, 0);
        acc2 = __builtin_amdgcn_mfma_f32_16x16x32_bf16(Al, B2h, acc2, 0, 0, 0);
        acc3 = __builtin_amdgcn_mfma_f32_16x16x32_bf16(Al, B3h, acc3, 0, 0, 0);
    }

    // ---- hT hi/lo transposed store ----
    {
        uint2 s01, s23;
        size_t off;
        s01 = splitpack2(acc0[0], acc0[1]); s23 = splitpack2(acc0[2], acc0[3]);
        off = (size_t)(0 * 16 + rsub) * N + wrow0 + g * 4;
        { uint2 ph; ph.x = s01.x; ph.y = s23.x; *(uint2*)(hT_hi + off) = ph; }
        { uint2 pl; pl.x = s01.y; pl.y = s23.y; *(uint2*)(hT_lo + off) = pl; }
        s01 = splitpack2(acc1[0], acc1[1]); s23 = splitpack2(acc1[2], acc1[3]);
        off = (size_t)(1 * 16 + rsub) * N + wrow0 + g * 4;
        { uint2 ph; ph.x = s01.x; ph.y = s23.x; *(uint2*)(hT_hi + off) = ph; }
        { uint2 pl; pl.x = s01.y; pl.y = s23.y; *(uint2*)(hT_lo + off) = pl; }
        s01 = splitpack2(acc2[0], acc2[1]); s23 = splitpack2(acc2[2], acc2[3]);
        off = (size_t)(2 * 16 + rsub) * N + wrow0 + g * 4;
        { uint2 ph; ph.x = s01.x; ph.y = s23.x; *(uint2*)(hT_hi + off) = ph; }
        { uint2 pl; pl.x = s01.y; pl.y = s23.y; *(uint2*)(hT_lo + off) = pl; }
        s01 = splitpack2(acc3[0], acc3[1]); s23 = splitpack2(acc3[2], acc3[3]);
        off = (size_t)(3 * 16 + rsub) * N + wrow0 + g * 4;
        { uint2 ph; ph.x = s01.x; ph.y = s23.x; *(uint2*)(hT_hi + off) = ph; }
        { uint2 pl; pl.x = s01.y; pl.y = s23.y; *(uint2*)(hT_lo + off) = pl; }
    }

    // ---- h1/h2 (scaled by LOG2E): per-lane partial, reduce across 16-lane group ----
    const float* af = (const float*)av;
    const unsigned short* au = (const unsigned short*)av;
    float a10 = isbf ? u2f(au[rsub])      : af[rsub];
    float a11 = isbf ? u2f(au[16 + rsub]) : af[16 + rsub];
    float a12 = isbf ? u2f(au[32 + rsub]) : af[32 + rsub];
    float a13 = isbf ? u2f(au[48 + rsub]) : af[48 + rsub];
    float a20 = isbf ? u2f(au[64 + rsub])  : af[64 + rsub];
    float a21 = isbf ? u2f(au[80 + rsub])  : af[80 + rsub];
    float a22 = isbf ? u2f(au[96 + rsub])  : af[96 + rsub];
    float a23 = isbf ? u2f(au[112 + rsub]) : af[112 + rsub];
    float s1r[4], s2r[4];
#pragma unroll
    for (int r = 0; r < 4; ++r) {
        s1r[r] = acc0[r] * a10 + acc1[r] * a11 + acc2[r] * a12 + acc3[r] * a13;
        s2r[r] = acc0[r] * a20 + acc1[r] * a21 + acc2[r] * a22 + acc3[r] * a23;
    }
#pragma unroll
    for (int off = 8; off; off >>= 1) {
#pragma unroll
        for (int r = 0; r < 4; ++r) {
            s1r[r] += __shfl_xor(s1r[r], off);
            s2r[r] += __shfl_xor(s2r[r], off);
        }
    }
    // scaled h2 wave-max -> one atomic per wave
    float wm = fmaxf(fmaxf(s2r[0], s2r[1]), fmaxf(s2r[2], s2r[3])) * LOG2E;
#pragma unroll
    for (int off = 32; off; off >>= 1) wm = fmaxf(wm, __shfl_xor(wm, off));
    if (lane == 0) atomicMax(h2enc, fenc(wm));

    if (rsub < 4) {
        float v1 = rsub == 0 ? s1r[0] : rsub == 1 ? s1r[1] : rsub == 2 ? s1r[2] : s1r[3];
        float v2 = rsub == 0 ? s2r[0] : rsub == 1 ? s2r[1] : rsub == 2 ? s2r[2] : s2r[3];
        h1[wrow0 + g * 4 + rsub] = v1 * LOG2E;
        h2[wrow0 + g * 4 + rsub] = v2 * LOG2E;
    }
}

// ---------- Kernel B: masked-exp GEMM via MFMA, M_rep=4 ----------
// Block = 64 rows; 4 waves split the k-range 4 ways; each wave computes 4 row-tiles
// (B-frags reused in REGISTERS across the 4 A-tiles -> 4x less hT traffic).
// Wave partials merged sequentially through a padded LDS tile, then one coalesced
// store to pacc[kbid]; k_out merges the nkb K-slots.
// All values pre-scaled by log2e: e = exp2(leaky(h1'+h2') - M'), exact softmax shift.
__global__ __launch_bounds__(256, 2) void k_attn(const int* __restrict__ adj,
                                                 const float* __restrict__ h1,
                                                 const float* __restrict__ h2,
                                                 const unsigned short* __restrict__ hT_hi,
                                                 const unsigned short* __restrict__ hT_lo,
                                                 const unsigned* __restrict__ h2enc,
                                                 float* __restrict__ pacc,
                                                 float* __restrict__ plner,
                                                 int klen) {
    __shared__ float accs[64][66];     // +2 pad: break g*4-row stride-64 bank aliasing
    __shared__ float lredL[4][64];

    const int wave = threadIdx.x >> 6;
    const int lane = threadIdx.x & 63;
    const int rsub = lane & 15;
    const int g = lane >> 4;
    const int row0 = blockIdx.x * 64;
    const int kbid = blockIdx.y;

    const float h2m = fdec(*h2enc);
    float h1r[4], c0[4];
#pragma unroll
    for (int mt = 0; mt < 4; ++mt) {
        h1r[mt] = h1[row0 + mt * 16 + rsub];
        float u = h1r[mt] + h2m;
        c0[mt] = -fmaxf(u, ALPHA * u);     // -M' (scaled leaky row-max bound)
    }

    f32x4 acc[4][4];
#pragma unroll
    for (int mt = 0; mt < 4; ++mt)
#pragma unroll
        for (int ct = 0; ct < 4; ++ct) acc[mt][ct] = (f32x4){0.f, 0.f, 0.f, 0.f};
    float lacc[4] = {0.f, 0.f, 0.f, 0.f};

    const unsigned short* bph = hT_hi + (size_t)rsub * N;
    const unsigned short* bpl = hT_lo + (size_t)rsub * N;

    const int kbeg = kbid * klen + wave * (klen >> 2);
    const int kend = kbeg + (klen >> 2);
    for (int k0 = kbeg; k0 < kend; k0 += 32) {
        const int kb = k0 + g * 8;

        // B-fragments: loaded once, reused by all 4 M-tiles
        const unsigned short* bh = bph + kb;
        const unsigned short* bl = bpl + kb;
        bf16x8 B0h = *(const bf16x8*)(bh);
        bf16x8 B1h = *(const bf16x8*)(bh + 16 * (size_t)N);
        bf16x8 B2h = *(const bf16x8*)(bh + 32 * (size_t)N);
        bf16x8 B3h = *(const bf16x8*)(bh + 48 * (size_t)N);
        bf16x8 B0l = *(const bf16x8*)(bl);
        bf16x8 B1l = *(const bf16x8*)(bl + 16 * (size_t)N);
        bf16x8 B2l = *(const bf16x8*)(bl + 32 * (size_t)N);
        bf16x8 B3l = *(const bf16x8*)(bl + 48 * (size_t)N);

        float4v hA = *(const float4v*)(h2 + kb);
        float4v hB = *(const float4v*)(h2 + kb + 4);

#pragma unroll
        for (int mt = 0; mt < 4; ++mt) {
            const size_t arow = (size_t)(row0 + mt * 16 + rsub) * N + kb;
            int4v aj0 = *(const int4v*)(adj + arow);
            int4v aj1 = *(const int4v*)(adj + arow + 4);

            float w[8];
#pragma unroll
            for (int j = 0; j < 4; ++j) {
                float u = h1r[mt] + hA[j];
                float s = fmaxf(u, ALPHA * u);
                float e = exp2f(s + c0[mt]);
                w[j] = aj0[j] > 0 ? e : 0.f;
            }
#pragma unroll
            for (int j = 0; j < 4; ++j) {
                float u = h1r[mt] + hB[j];
                float s = fmaxf(u, ALPHA * u);
                float e = exp2f(s + c0[mt]);
                w[4 + j] = aj1[j] > 0 ? e : 0.f;
            }
#pragma unroll
            for (int j = 0; j < 8; ++j) lacc[mt] += w[j];

            uint2 p0 = splitpack2(w[0], w[1]);
            uint2 p1 = splitpack2(w[2], w[3]);
            uint2 p2 = splitpack2(w[4], w[5]);
            uint2 p3 = splitpack2(w[6], w[7]);
            bf16x8 Ahi = as_bf16x8((int)p0.x, (int)p1.x, (int)p2.x, (int)p3.x);
            bf16x8 Alo = as_bf16x8((int)p0.y, (int)p1.y, (int)p2.y, (int)p3.y);

            acc[mt][0] = __builtin_amdgcn_mfma_f32_16x16x32_bf16(Ahi, B0h, acc[mt][0], 0, 0, 0);
            acc[mt][1] = __builtin_amdgcn_mfma_f32_16x16x32_bf16(Ahi, B1h, acc[mt][1], 0, 0, 0);
            acc[mt][2] = __builtin_amdgcn_mfma_f32_16x16x32_bf16(Ahi, B2h, acc[mt][2], 0, 0, 0);
            acc[mt][3] = __builtin_amdgcn_mfma_f32_16x16x32_bf16(Ahi, B3h, acc[mt][3], 0, 0, 0);
            acc[mt][0] = __builtin_amdgcn_mfma_f32_16x16x32_bf16(Ahi, B0l, acc[mt][0], 0, 0, 0);
            acc[mt][1] = __builtin_amdgcn_mfma_f32_16x16x32_bf16(Ahi, B1l, acc[mt][1], 0, 0, 0);
            acc[mt][2] = __builtin_amdgcn_mfma_f32_16x16x32_bf16(Ahi, B2l, acc[mt][2], 0, 0, 0);
            acc[mt][3] = __builtin_amdgcn_mfma_f32_16x16x32_bf16(Ahi, B3l, acc[mt][3], 0, 0, 0);
            acc[mt][0] = __builtin_amdgcn_mfma_f32_16x16x32_bf16(Alo, B0h, acc[mt][0], 0, 0, 0);
            acc[mt][1] = __builtin_amdgcn_mfma_f32_16x16x32_bf16(Alo, B1h, acc[mt][1], 0, 0, 0);
            acc[mt][2] = __builtin_amdgcn_mfma_f32_16x16x32_bf16(Alo, B2h, acc[mt][2], 0, 0, 0);
            acc[mt][3] = __builtin_amdgcn_mfma_f32_16x16x32_bf16(Alo, B3h, acc[mt][3], 0, 0, 0);
        }
    }

    // denominator partials: reduce over the 4 k-groups, one row per (mt, rsub)
#pragma unroll
    for (int mt = 0; mt < 4; ++mt) {
        float l = lacc[mt];
        l += __shfl_xor(l, 16);
        l += __shfl_xor(l, 32);
        if (g == 0) lredL[wave][mt * 16 + rsub] = l;
    }

    // sequential LDS merge of the 4 K-partials (rows shared across waves)
    if (wave == 0) {
#pragma unroll
        for (int mt = 0; mt < 4; ++mt)
#pragma unroll
            for (int ct = 0; ct < 4; ++ct)
#pragma unroll
                for (int r = 0; r < 4; ++r)
                    accs[mt * 16 + g * 4 + r][ct * 16 + rsub] = acc[mt][ct][r];
    }
    __syncthreads();
#pragma unroll
    for (int w2 = 1; w2 < 4; ++w2) {
        if (wave == w2) {
#pragma unroll
            for (int mt = 0; mt < 4; ++mt)
#pragma unroll
                for (int ct = 0; ct < 4; ++ct)
#pragma unroll
                    for (int r = 0; r < 4; ++r)
                        accs[mt * 16 + g * 4 + r][ct * 16 + rsub] += acc[mt][ct][r];
        }
        __syncthreads();
    }

    // coalesced writeout of the block's 64x64 tile + row denominators
    float* pa = pacc + (size_t)kbid * (N * OUT_DIM);
#pragma unroll
    for (int p = 0; p < 16; ++p) {
        int idx = p * 256 + threadIdx.x;
        int rl = idx >> 6, col = idx & 63;
        pa[(size_t)(row0 + rl) * OUT_DIM + col] = accs[rl][col];
    }
    if (threadIdx.x < 64)
        plner[(size_t)kbid * N + row0 + threadIdx.x] =
            lredL[0][threadIdx.x] + lredL[1][threadIdx.x] + lredL[2][threadIdx.x] + lredL[3][threadIdx.x];
}

// ---------- Kernel C: merge K-partials, normalize, ELU, store ----------
__global__ __launch_bounds__(256) void k_out(const float* __restrict__ pacc,
                                             const float* __restrict__ plner,
                                             const int* __restrict__ flag,
                                             void* __restrict__ outv,
                                             int nkb) {
    int idx = blockIdx.x * 256 + threadIdx.x;
    int row = idx >> 6;
    float v = 0.f, l = 0.f;
    for (int kb = 0; kb < nkb; ++kb) {
        v += pacc[(size_t)kb * (N * OUT_DIM) + idx];
        l += plner[(size_t)kb * N + row];
    }
    float o = l > 0.f ? v / l : 0.f;
    o = o > 0.f ? o : exp2f(o * LOG2E) - 1.f;               // ELU
    if (*flag) ((bf16*)outv)[idx] = __float2bfloat16(o);
    else       ((float*)outv)[idx] = o;
}

extern "C" void kernel_launch(void* const* d_in, const int* in_sizes, int n_in,
                              void* d_out, int out_size, void* d_ws, size_t ws_size,
                              hipStream_t stream) {
    const void* feat = d_in[0];
    const int* adj = (const int*)d_in[1];
    const void* W = d_in[2];
    const void* a = d_in[3];

    char* ws = (char*)d_ws;
    int*      flag  = (int*)(ws);
    unsigned* h2enc = (unsigned*)(ws + 256);
    float* h1       = (float*)(ws + 4096);                              // 32 KB
    float* h2       = (float*)(ws + 36864);                             // 32 KB
    unsigned short* hT_hi = (unsigned short*)(ws + 69632);              // 1 MB
    unsigned short* hT_lo = (unsigned short*)(ws + 69632 + 1048576);    // 1 MB
    unsigned short* WT_hi = (unsigned short*)(ws + 2166784);            // 64 KB
    unsigned short* WT_lo = (unsigned short*)(ws + 2166784 + 65536);    // 64 KB
    char* dynbase = ws + 2297856;

    size_t cap = ws_size ? ws_size : ((size_t)1 << 30);
    int nkb = 8;
    while (nkb > 1) {
        size_t need = 2297856 + (size_t)nkb * ((size_t)N * OUT_DIM * 4 + (size_t)N * 4);
        if (need <= cap) break;
        nkb >>= 1;
    }
    float* pacc  = (float*)dynbase;
    float* plner = (float*)(dynbase + (size_t)nkb * N * OUT_DIM * 4);

    hipLaunchKernelGGL(k_sniff, dim3(1), dim3(64), 0, stream,
                       (const unsigned short*)feat, flag);
    hipLaunchKernelGGL(k_prep, dim3((IN_DIM * OUT_DIM) / 256), dim3(256), 0, stream,
                       W, flag, WT_hi, WT_lo, h2enc);
    hipLaunchKernelGGL(k_h, dim3(N / 16), dim3(64), 0, stream,
                       feat, WT_hi, WT_lo, a, flag, h1, h2, hT_hi, hT_lo, h2enc);
    hipLaunchKernelGGL(k_attn, dim3(N / 64, nkb), dim3(256), 0, stream,
                       adj, h1, h2, hT_hi, hT_lo, h2enc, pacc, plner, N / nkb);
    hipLaunchKernelGGL(k_out, dim3((N * OUT_DIM) / 256), dim3(256), 0, stream,
                       pacc, plner, flag, d_out, nkb);
}

// Round 5
// 417.841 us; speedup vs baseline: 2.4897x; 1.0055x over previous
//
#include <hip/hip_runtime.h>
#include <hip/hip_bf16.h>

#define N 8192
#define IN_DIM 512
#define OUT_DIM 64
#define ALPHA 0.2f
#define LOG2E 1.44269504f

typedef __hip_bfloat16 bf16;
typedef __attribute__((ext_vector_type(8))) short bf16x8;   // 8 bf16 = 4 VGPRs (MFMA A/B frag)
typedef __attribute__((ext_vector_type(4))) float f32x4;    // MFMA C/D frag
typedef __attribute__((ext_vector_type(4))) int   int4v;
typedef __attribute__((ext_vector_type(4))) float float4v;

__device__ __forceinline__ float u2f(unsigned short u) {
    union { unsigned int i; float f; } c; c.i = ((unsigned int)u) << 16; return c.f;
}

// Exact truncation hi/lo split of two fp32 into packed bf16 words.
__device__ __forceinline__ uint2 splitpack2(float f0, float f1) {
    unsigned u0 = __float_as_uint(f0), u1 = __float_as_uint(f1);
    unsigned h0 = u0 & 0xFFFF0000u, h1 = u1 & 0xFFFF0000u;
    float l0 = f0 - __uint_as_float(h0);
    float l1 = f1 - __uint_as_float(h1);
    uint2 r;
    r.x = (h0 >> 16) | h1;
    r.y = (__float_as_uint(l0) >> 16) | (__float_as_uint(l1) & 0xFFFF0000u);
    return r;
}

__device__ __forceinline__ bf16x8 as_bf16x8(int a, int b, int c, int d) {
    union { int4v i; bf16x8 b; } u;
    u.i = (int4v){a, b, c, d};
    return u.b;
}

// ordered-float <-> unsigned monotone encoding (for atomicMax on float)
__device__ __forceinline__ unsigned fenc(float f) {
    unsigned u = __float_as_uint(f);
    return (u & 0x80000000u) ? ~u : (u | 0x80000000u);
}
__device__ __forceinline__ float fdec(unsigned e) {
    return (e & 0x80000000u) ? __uint_as_float(e & 0x7FFFFFFFu) : __uint_as_float(~e);
}

// ---------- dtype sniffer: flag=1 if float inputs are bf16, 0 if fp32 ----------
__global__ void k_sniff(const unsigned short* __restrict__ feat_u16, int* __restrict__ flag) {
    int lane = threadIdx.x;  // 64 threads, 1 wave
    float v = u2f(feat_u16[2 * lane]);
    float av = fabsf(v);
    int ok = (v == 0.f) || (av > 1e-8f && av < 1e8f);
    unsigned long long m = __ballot(ok);
    if (lane == 0) *flag = (__popcll(m) >= 48) ? 1 : 0;
}

// ---------- prep: W [512][64] -> WT hi/lo [64][512] bf16; init h2max encoder ----------
__global__ __launch_bounds__(256) void k_prep(const void* __restrict__ Wv,
                                              const int* __restrict__ flag,
                                              unsigned short* __restrict__ WT_hi,
                                              unsigned short* __restrict__ WT_lo,
                                              unsigned* __restrict__ h2enc) {
    if (blockIdx.x == 0 && threadIdx.x == 0) *h2enc = fenc(-3e38f);
    int idx = blockIdx.x * 256 + threadIdx.x;     // 0..32767
    int k = idx >> 6, c = idx & 63;
    float w = (*flag) ? u2f(((const unsigned short*)Wv)[idx]) : ((const float*)Wv)[idx];
    unsigned u = __float_as_uint(w);
    unsigned hi = u & 0xFFFF0000u;
    float lo = w - __uint_as_float(hi);
    WT_hi[c * IN_DIM + k] = (unsigned short)(hi >> 16);
    WT_lo[c * IN_DIM + k] = (unsigned short)(__float_as_uint(lo) >> 16);
}

// ---------- Kernel A (MFMA): h = feat @ W; hT hi/lo; h1,h2 (pre-scaled by log2e) ----------
// Block = 256 thr (4 waves), 16 rows. Waves split K=512 four ways (4 k-steps each),
// merge through padded LDS; epilogue once per block from the merged tile.
// 2048 waves total = 8 waves/CU (vs 2 before) -> latency actually hidden.
__global__ __launch_bounds__(256) void k_h(const void* __restrict__ featv,
                                           const unsigned short* __restrict__ WT_hi,
                                           const unsigned short* __restrict__ WT_lo,
                                           const void* __restrict__ av,
                                           const int* __restrict__ flag,
                                           float* __restrict__ h1,
                                           float* __restrict__ h2,
                                           unsigned short* __restrict__ hT_hi,
                                           unsigned short* __restrict__ hT_lo,
                                           unsigned* __restrict__ h2enc) {
    __shared__ float C[16][66];        // merged h tile, +2 pad
    const int tid = threadIdx.x;
    const int wave = tid >> 6;
    const int lane = tid & 63;
    const int rsub = lane & 15;
    const int g = lane >> 4;
    const int wrow0 = blockIdx.x * 16;
    const int isbf = *flag;

    f32x4 acc0 = {0.f,0.f,0.f,0.f}, acc1 = {0.f,0.f,0.f,0.f};
    f32x4 acc2 = {0.f,0.f,0.f,0.f}, acc3 = {0.f,0.f,0.f,0.f};

    const int kbeg = wave * (IN_DIM / 4);
    for (int k0 = kbeg; k0 < kbeg + IN_DIM / 4; k0 += 32) {
        const int ka = k0 + g * 8;
        bf16x8 Ah, Al;
        if (isbf) {
            Ah = *(const bf16x8*)((const unsigned short*)featv + (size_t)(wrow0 + rsub) * IN_DIM + ka);
            Al = as_bf16x8(0, 0, 0, 0);
        } else {
            const float* fp = (const float*)featv + (size_t)(wrow0 + rsub) * IN_DIM + ka;
            float4v f0 = *(const float4v*)fp;
            float4v f1 = *(const float4v*)(fp + 4);
            uint2 q0 = splitpack2(f0[0], f0[1]);
            uint2 q1 = splitpack2(f0[2], f0[3]);
            uint2 q2 = splitpack2(f1[0], f1[1]);
            uint2 q3 = splitpack2(f1[2], f1[3]);
            Ah = as_bf16x8((int)q0.x, (int)q1.x, (int)q2.x, (int)q3.x);
            Al = as_bf16x8((int)q0.y, (int)q1.y, (int)q2.y, (int)q3.y);
        }
        const unsigned short* wh = WT_hi + (size_t)rsub * IN_DIM + ka;
        const unsigned short* wl = WT_lo + (size_t)rsub * IN_DIM + ka;
        bf16x8 B0h = *(const bf16x8*)(wh);
        bf16x8 B1h = *(const bf16x8*)(wh + 16 * IN_DIM);
        bf16x8 B2h = *(const bf16x8*)(wh + 32 * IN_DIM);
        bf16x8 B3h = *(const bf16x8*)(wh + 48 * IN_DIM);
        bf16x8 B0l = *(const bf16x8*)(wl);
        bf16x8 B1l = *(const bf16x8*)(wl + 16 * IN_DIM);
        bf16x8 B2l = *(const bf16x8*)(wl + 32 * IN_DIM);
        bf16x8 B3l = *(const bf16x8*)(wl + 48 * IN_DIM);

        acc0 = __builtin_amdgcn_mfma_f32_16x16x32_bf16(Ah, B0h, acc0, 0, 0, 0);
        acc1 = __builtin_amdgcn_mfma_f32_16x16x32_bf16(Ah, B1h, acc1, 0, 0, 0);
        acc2 = __builtin_amdgcn_mfma_f32_16x16x32_bf16(Ah, B2h, acc2, 0, 0, 0);
        acc3 = __builtin_amdgcn_mfma_f32_16x16x32_bf16(Ah, B3h, acc3, 0, 0, 0);
        acc0 = __builtin_amdgcn_mfma_f32_16x16x32_bf16(Ah, B0l, acc0, 0, 0, 0);
        acc1 = __builtin_amdgcn_mfma_f32_16x16x32_bf16(Ah, B1l, acc1, 0, 0, 0);
        acc2 = __builtin_amdgcn_mfma_f32_16x16x32_bf16(Ah, B2l, acc2, 0, 0, 0);
        acc3 = __builtin_amdgcn_mfma_f32_16x16x32_bf16(Ah, B3l, acc3, 0, 0, 0);
        acc0 = __builtin_amdgcn_mfma_f32_16x16x32_bf16(Al, B0h, acc0, 0, 0, 0);
        acc1 = __builtin_amdgcn_mfma_f32_16x16x32_bf16(Al, B1h, acc1, 0, 0, 0);
        acc2 = __builtin_amdgcn_mfma_f32_16x16x32_bf16(Al, B2h, acc2, 0, 0, 0);
        acc3 = __builtin_amdgcn_mfma_f32_16x16x32_bf16(Al, B3h, acc3, 0, 0, 0);
    }

    // merge the 4 K-partials through LDS (C/D layout: col=lane&15, row=4*g+reg)
    if (wave == 0) {
#pragma unroll
        for (int r = 0; r < 4; ++r) {
            C[g * 4 + r][rsub]      = acc0[r];
            C[g * 4 + r][16 + rsub] = acc1[r];
            C[g * 4 + r][32 + rsub] = acc2[r];
            C[g * 4 + r][48 + rsub] = acc3[r];
        }
    }
    __syncthreads();
#pragma unroll
    for (int w2 = 1; w2 < 4; ++w2) {
        if (wave == w2) {
#pragma unroll
            for (int r = 0; r < 4; ++r) {
                C[g * 4 + r][rsub]      += acc0[r];
                C[g * 4 + r][16 + rsub] += acc1[r];
                C[g * 4 + r][32 + rsub] += acc2[r];
                C[g * 4 + r][48 + rsub] += acc3[r];
            }
        }
        __syncthreads();
    }

    // ---- epilogue 1: hT hi/lo split-stores, all 256 threads (4 rows x 1 col each) ----
    {
        int c = tid >> 2;
        int r0 = (tid & 3) * 4;
        float v0 = C[r0 + 0][c], v1 = C[r0 + 1][c], v2 = C[r0 + 2][c], v3 = C[r0 + 3][c];
        uint2 s01 = splitpack2(v0, v1);
        uint2 s23 = splitpack2(v2, v3);
        size_t off = (size_t)c * N + wrow0 + r0;
        { uint2 ph; ph.x = s01.x; ph.y = s23.x; *(uint2*)(hT_hi + off) = ph; }
        { uint2 pl; pl.x = s01.y; pl.y = s23.y; *(uint2*)(hT_lo + off) = pl; }
    }

    // ---- epilogue 2: h1/h2 (scaled by LOG2E) + h2 global max, wave 0 lanes 0-15 ----
    if (wave == 0 && lane < 16) {
        const float* af = (const float*)av;
        const unsigned short* au = (const unsigned short*)av;
        float s1 = 0.f, s2 = 0.f;
#pragma unroll 8
        for (int c = 0; c < 64; ++c) {
            float a1 = isbf ? u2f(au[c])      : af[c];
            float a2 = isbf ? u2f(au[64 + c]) : af[64 + c];
            float hv = C[lane][c];
            s1 += hv * a1;
            s2 += hv * a2;
        }
        s1 *= LOG2E; s2 *= LOG2E;
        h1[wrow0 + lane] = s1;
        h2[wrow0 + lane] = s2;
        float wm = s2;
#pragma unroll
        for (int off = 8; off; off >>= 1) wm = fmaxf(wm, __shfl_xor(wm, off));
        if (lane == 0) atomicMax(h2enc, fenc(wm));
    }
}

// ---------- Kernel B: masked-exp GEMM via MFMA, M_rep=4 ----------
// Block = 64 rows; 4 waves split the k-range 4 ways; each wave computes 4 row-tiles
// (B-frags reused in REGISTERS across the 4 A-tiles -> 4x less hT traffic).
// All values pre-scaled by log2e: e = exp2(leaky(h1'+h2') - M'), exact softmax shift.
__global__ __launch_bounds__(256, 2) void k_attn(const int* __restrict__ adj,
                                                 const float* __restrict__ h1,
                                                 const float* __restrict__ h2,
                                                 const unsigned short* __restrict__ hT_hi,
                                                 const unsigned short* __restrict__ hT_lo,
                                                 const unsigned* __restrict__ h2enc,
                                                 float* __restrict__ pacc,
                                                 float* __restrict__ plner,
                                                 int klen) {
    __shared__ float accs[64][66];     // +2 pad: break g*4-row stride-64 bank aliasing
    __shared__ float lredL[4][64];

    const int wave = threadIdx.x >> 6;
    const int lane = threadIdx.x & 63;
    const int rsub = lane & 15;
    const int g = lane >> 4;
    const int row0 = blockIdx.x * 64;
    const int kbid = blockIdx.y;

    const float h2m = fdec(*h2enc);
    float h1r[4], c0[4];
#pragma unroll
    for (int mt = 0; mt < 4; ++mt) {
        h1r[mt] = h1[row0 + mt * 16 + rsub];
        float u = h1r[mt] + h2m;
        c0[mt] = -fmaxf(u, ALPHA * u);     // -M' (scaled leaky row-max bound)
    }

    f32x4 acc[4][4];
#pragma unroll
    for (int mt = 0; mt < 4; ++mt)
#pragma unroll
        for (int ct = 0; ct < 4; ++ct) acc[mt][ct] = (f32x4){0.f, 0.f, 0.f, 0.f};
    float lacc[4] = {0.f, 0.f, 0.f, 0.f};

    const unsigned short* bph = hT_hi + (size_t)rsub * N;
    const unsigned short* bpl = hT_lo + (size_t)rsub * N;

    const int kbeg = kbid * klen + wave * (klen >> 2);
    const int kend = kbeg + (klen >> 2);
    for (int k0 = kbeg; k0 < kend; k0 += 32) {
        const int kb = k0 + g * 8;

        // B-fragments: loaded once, reused by all 4 M-tiles
        const unsigned short* bh = bph + kb;
        const unsigned short* bl = bpl + kb;
        bf16x8 B0h = *(const bf16x8*)(bh);
        bf16x8 B1h = *(const bf16x8*)(bh + 16 * (size_t)N);
        bf16x8 B2h = *(const bf16x8*)(bh + 32 * (size_t)N);
        bf16x8 B3h = *(const bf16x8*)(bh + 48 * (size_t)N);
        bf16x8 B0l = *(const bf16x8*)(bl);
        bf16x8 B1l = *(const bf16x8*)(bl + 16 * (size_t)N);
        bf16x8 B2l = *(const bf16x8*)(bl + 32 * (size_t)N);
        bf16x8 B3l = *(const bf16x8*)(bl + 48 * (size_t)N);

        float4v hA = *(const float4v*)(h2 + kb);
        float4v hB = *(const float4v*)(h2 + kb + 4);

#pragma unroll
        for (int mt = 0; mt < 4; ++mt) {
            const size_t arow = (size_t)(row0 + mt * 16 + rsub) * N + kb;
            int4v aj0 = *(const int4v*)(adj + arow);
            int4v aj1 = *(const int4v*)(adj + arow + 4);

            float w[8];
#pragma unroll
            for (int j = 0; j < 4; ++j) {
                float u = h1r[mt] + hA[j];
                float s = fmaxf(u, ALPHA * u);
                float e = exp2f(s + c0[mt]);
                w[j] = aj0[j] > 0 ? e : 0.f;
            }
#pragma unroll
            for (int j = 0; j < 4; ++j) {
                float u = h1r[mt] + hB[j];
                float s = fmaxf(u, ALPHA * u);
                float e = exp2f(s + c0[mt]);
                w[4 + j] = aj1[j] > 0 ? e : 0.f;
            }
#pragma unroll
            for (int j = 0; j < 8; ++j) lacc[mt] += w[j];

            uint2 p0 = splitpack2(w[0], w[1]);
            uint2 p1 = splitpack2(w[2], w[3]);
            uint2 p2 = splitpack2(w[4], w[5]);
            uint2 p3 = splitpack2(w[6], w[7]);
            bf16x8 Ahi = as_bf16x8((int)p0.x, (int)p1.x, (int)p2.x, (int)p3.x);
            bf16x8 Alo = as_bf16x8((int)p0.y, (int)p1.y, (int)p2.y, (int)p3.y);

            acc[mt][0] = __builtin_amdgcn_mfma_f32_16x16x32_bf16(Ahi, B0h, acc[mt][0], 0, 0, 0);
            acc[mt][1] = __builtin_amdgcn_mfma_f32_16x16x32_bf16(Ahi, B1h, acc[mt][1], 0, 0, 0);
            acc[mt][2] = __builtin_amdgcn_mfma_f32_16x16x32_bf16(Ahi, B2h, acc[mt][2], 0, 0, 0);
            acc[mt][3] = __builtin_amdgcn_mfma_f32_16x16x32_bf16(Ahi, B3h, acc[mt][3], 0, 0, 0);
            acc[mt][0] = __builtin_amdgcn_mfma_f32_16x16x32_bf16(Ahi, B0l, acc[mt][0], 0, 0, 0);
            acc[mt][1] = __builtin_amdgcn_mfma_f32_16x16x32_bf16(Ahi, B1l, acc[mt][1], 0, 0, 0);
            acc[mt][2] = __builtin_amdgcn_mfma_f32_16x16x32_bf16(Ahi, B2l, acc[mt][2], 0, 0, 0);
            acc[mt][3] = __builtin_amdgcn_mfma_f32_16x16x32_bf16(Ahi, B3l, acc[mt][3], 0, 0, 0);
            acc[mt][0] = __builtin_amdgcn_mfma_f32_16x16x32_bf16(Alo, B0h, acc[mt][0], 0, 0, 0);
            acc[mt][1] = __builtin_amdgcn_mfma_f32_16x16x32_bf16(Alo, B1h, acc[mt][1], 0, 0, 0);
            acc[mt][2] = __builtin_amdgcn_mfma_f32_16x16x32_bf16(Alo, B2h, acc[mt][2], 0, 0, 0);
            acc[mt][3] = __builtin_amdgcn_mfma_f32_16x16x32_bf16(Alo, B3h, acc[mt][3], 0, 0, 0);
        }
    }

    // denominator partials: reduce over the 4 k-groups, one row per (mt, rsub)
#pragma unroll
    for (int mt = 0; mt < 4; ++mt) {
        float l = lacc[mt];
        l += __shfl_xor(l, 16);
        l += __shfl_xor(l, 32);
        if (g == 0) lredL[wave][mt * 16 + rsub] = l;
    }

    // sequential LDS merge of the 4 K-partials (rows shared across waves)
    if (wave == 0) {
#pragma unroll
        for (int mt = 0; mt < 4; ++mt)
#pragma unroll
            for (int ct = 0; ct < 4; ++ct)
#pragma unroll
                for (int r = 0; r < 4; ++r)
                    accs[mt * 16 + g * 4 + r][ct * 16 + rsub] = acc[mt][ct][r];
    }
    __syncthreads();
#pragma unroll
    for (int w2 = 1; w2 < 4; ++w2) {
        if (wave == w2) {
#pragma unroll
            for (int mt = 0; mt < 4; ++mt)
#pragma unroll
                for (int ct = 0; ct < 4; ++ct)
#pragma unroll
                    for (int r = 0; r < 4; ++r)
                        accs[mt * 16 + g * 4 + r][ct * 16 + rsub] += acc[mt][ct][r];
        }
        __syncthreads();
    }

    // coalesced writeout of the block's 64x64 tile + row denominators
    float* pa = pacc + (size_t)kbid * (N * OUT_DIM);
#pragma unroll
    for (int p = 0; p < 16; ++p) {
        int idx = p * 256 + threadIdx.x;
        int rl = idx >> 6, col = idx & 63;
        pa[(size_t)(row0 + rl) * OUT_DIM + col] = accs[rl][col];
    }
    if (threadIdx.x < 64)
        plner[(size_t)kbid * N + row0 + threadIdx.x] =
            lredL[0][threadIdx.x] + lredL[1][threadIdx.x] + lredL[2][threadIdx.x] + lredL[3][threadIdx.x];
}

// ---------- Kernel C: merge K-partials, normalize, ELU, store ----------
__global__ __launch_bounds__(256) void k_out(const float* __restrict__ pacc,
                                             const float* __restrict__ plner,
                                             const int* __restrict__ flag,
                                             void* __restrict__ outv,
                                             int nkb) {
    int idx = blockIdx.x * 256 + threadIdx.x;
    int row = idx >> 6;
    float v = 0.f, l = 0.f;
    for (int kb = 0; kb < nkb; ++kb) {
        v += pacc[(size_t)kb * (N * OUT_DIM) + idx];
        l += plner[(size_t)kb * N + row];
    }
    float o = l > 0.f ? v / l : 0.f;
    o = o > 0.f ? o : exp2f(o * LOG2E) - 1.f;               // ELU
    if (*flag) ((bf16*)outv)[idx] = __float2bfloat16(o);
    else       ((float*)outv)[idx] = o;
}

extern "C" void kernel_launch(void* const* d_in, const int* in_sizes, int n_in,
                              void* d_out, int out_size, void* d_ws, size_t ws_size,
                              hipStream_t stream) {
    const void* feat = d_in[0];
    const int* adj = (const int*)d_in[1];
    const void* W = d_in[2];
    const void* a = d_in[3];

    char* ws = (char*)d_ws;
    int*      flag  = (int*)(ws);
    unsigned* h2enc = (unsigned*)(ws + 256);
    float* h1       = (float*)(ws + 4096);                              // 32 KB
    float* h2       = (float*)(ws + 36864);                             // 32 KB
    unsigned short* hT_hi = (unsigned short*)(ws + 69632);              // 1 MB
    unsigned short* hT_lo = (unsigned short*)(ws + 69632 + 1048576);    // 1 MB
    unsigned short* WT_hi = (unsigned short*)(ws + 2166784);            // 64 KB
    unsigned short* WT_lo = (unsigned short*)(ws + 2166784 + 65536);    // 64 KB
    char* dynbase = ws + 2297856;

    size_t cap = ws_size ? ws_size : ((size_t)1 << 30);
    int nkb = 8;
    while (nkb > 1) {
        size_t need = 2297856 + (size_t)nkb * ((size_t)N * OUT_DIM * 4 + (size_t)N * 4);
        if (need <= cap) break;
        nkb >>= 1;
    }
    float* pacc  = (float*)dynbase;
    float* plner = (float*)(dynbase + (size_t)nkb * N * OUT_DIM * 4);

    hipLaunchKernelGGL(k_sniff, dim3(1), dim3(64), 0, stream,
                       (const unsigned short*)feat, flag);
    hipLaunchKernelGGL(k_prep, dim3((IN_DIM * OUT_DIM) / 256), dim3(256), 0, stream,
                       W, flag, WT_hi, WT_lo, h2enc);
    hipLaunchKernelGGL(k_h, dim3(N / 16), dim3(256), 0, stream,
                       feat, WT_hi, WT_lo, a, flag, h1, h2, hT_hi, hT_lo, h2enc);
    hipLaunchKernelGGL(k_attn, dim3(N / 64, nkb), dim3(256), 0, stream,
                       adj, h1, h2, hT_hi, hT_lo, h2enc, pacc, plner, N / nkb);
    hipLaunchKernelGGL(k_out, dim3((N * OUT_DIM) / 256), dim3(256), 0, stream,
                       pacc, plner, flag, d_out, nkb);
}